// Round 4
// baseline (122.359 us; speedup 1.0000x reference)
//
#include <hip/hip_runtime.h>
#include <hip/hip_fp16.h>
#include <math.h>

// AdjustNet: B=32, L=512, C=256, N=16 — f16 MFMA pipeline, fused sample_layer
//  K0: transpose+cast weights AND query -> w1T[128][512], w2T[512][128],
//      w3T[256][256], w4T[32][256], qT[32][256][512] (all f16)
//  K12: per (b, 16-c tile): t1 = gelu(LN_128(qT@w1+b1)) kept in LDS;
//       q[b,l,c-tile] = t1 @ w2 + b2 (both MFMA)
//  K3: h=q@w3+b3, LN_256, gelu -> ts; a=ts@w4+b4 (MFMA); tanh*0.02; pos epilogue
//  K4: out[b,l,n,:] = w0*x[b,c0,:] + w1*x[b,c1,:]

typedef _Float16 f16;
typedef _Float16 f16x8 __attribute__((ext_vector_type(8)));
typedef float f32x4 __attribute__((ext_vector_type(4)));

#define ZERO4 f32x4{0.f, 0.f, 0.f, 0.f}

__device__ __forceinline__ float gelu_exact(float v) {
  return 0.5f * v * (1.0f + erff(v * 0.70710678118654752f));
}

// ---------------------------------------------------------------- K0
// blocks 0..51: weight transpose-cast (64x64 tiles). blocks 52..1075: query.
__global__ __launch_bounds__(256) void k0_prep(
    const float* __restrict__ w1, const float* __restrict__ w2,
    const float* __restrict__ w3, const float* __restrict__ w4,
    const float* __restrict__ query,
    f16* __restrict__ w1T, f16* __restrict__ w2T,
    f16* __restrict__ w3T, f16* __restrict__ w4T, f16* __restrict__ qT) {
  __shared__ f16 tile[64][80];
  int blk = blockIdx.x;
  const int tid = threadIdx.x;
  if (blk < 52) {
    const float* in; f16* out; int R, Cc, tr, tc;
    if (blk < 16)      { in = w1; out = w1T; R = 512; Cc = 128; tr = blk >> 1; tc = blk & 1; }
    else if (blk < 32) { blk -= 16; in = w2; out = w2T; R = 128; Cc = 512; tr = blk >> 3; tc = blk & 7; }
    else if (blk < 48) { blk -= 32; in = w3; out = w3T; R = 256; Cc = 256; tr = blk >> 2; tc = blk & 3; }
    else               { blk -= 48; in = w4; out = w4T; R = 256; Cc = 32;  tr = blk;      tc = 0; }
    const int r0 = tr * 64, c0 = tc * 64;
    for (int id = tid; id < 4096; id += 256) {
      int rr = id >> 6, cc = id & 63;
      if (c0 + cc < Cc) tile[cc][rr] = (f16)in[(r0 + rr) * Cc + c0 + cc];
    }
    __syncthreads();
    for (int id = tid; id < 512; id += 256) {
      int cc = id >> 3, ch = id & 7;
      if (c0 + cc < Cc)
        *(f16x8*)(out + (c0 + cc) * R + r0 + ch * 8) = *(f16x8*)&tile[cc][ch * 8];
    }
  } else {
    blk -= 52;
    const int b = blk >> 5, t = blk & 31;
    const int l0 = (t >> 2) << 6, c0 = (t & 3) << 6;
    for (int id = tid; id < 4096; id += 256) {
      int rr = id >> 6, cc = id & 63;   // rr = l, cc = c
      tile[cc][rr] = (f16)query[((b << 9) + l0 + rr) * 256 + c0 + cc];
    }
    __syncthreads();
    for (int id = tid; id < 512; id += 256) {
      int cc = id >> 3, ch = id & 7;
      *(f16x8*)(qT + ((b << 8) + c0 + cc) * 512 + l0 + ch * 8) = *(f16x8*)&tile[cc][ch * 8];
    }
  }
}

// ---------------------------------------------------------------- K12
// grid 512: b = blk>>4, c0 = (blk&15)*16.
// phase1: t1[16 c][128 j] = gelu(LN(qT@w1+b1))  (M=16,N=128,K=512) -> LDS
// phase2: q[l][c-tile] = t1 @ w2 + b2           (M=512 in 4 chunks,N=16,K=128)
__global__ __launch_bounds__(256) void k12_sample(
    const f16* __restrict__ qT, const f16* __restrict__ w1T,
    const f16* __restrict__ w2T,
    const float* __restrict__ b1, const float* __restrict__ g1,
    const float* __restrict__ bt1, const float* __restrict__ b2,
    f16* __restrict__ qout) {
  __shared__ char pool[38912];
  // [0,32768): ph1 At(2KB)+Bt(16KB) / hs overlay / ph2 At2(32KB)
  // [32768,36864): t1s 16 rows x 256B ; [36864,38912): sb2 512 f32
  const int tid = threadIdx.x;
  const int b = blockIdx.x >> 4;
  const int c0 = (blockIdx.x & 15) << 4;
  const int lane = tid & 63, w = tid >> 6;
  const int mrow = lane & 15, kg = lane >> 4;
  char* At = pool;
  char* Bt = pool + 2048;
  char* t1s = pool + 32768;
  float* sb2 = (float*)(pool + 36864);

  sb2[tid] = b2[tid];
  sb2[tid + 256] = b2[tid + 256];

  f32x4 acc[2] = {ZERO4, ZERO4};
  for (int s = 0; s < 8; ++s) {
    const int k0 = s << 6;
    if (tid < 128) {
      int r = tid >> 3, c = tid & 7;
      f16x8 v = *(const f16x8*)(qT + ((b << 8) + c0 + r) * 512 + k0 + c * 8);
      *(f16x8*)(At + r * 128 + ((c * 16) ^ ((r & 7) << 4))) = v;
    }
    for (int id = tid; id < 1024; id += 256) {
      int rj = id >> 3, c = id & 7;
      f16x8 v = *(const f16x8*)(w1T + rj * 512 + k0 + c * 8);
      *(f16x8*)(Bt + rj * 128 + ((c * 16) ^ ((rj & 7) << 4))) = v;
    }
    __syncthreads();
#pragma unroll
    for (int kk = 0; kk < 2; ++kk) {
      f16x8 a = *(const f16x8*)(At + mrow * 128 + (((kk << 6) + (kg << 4)) ^ ((mrow & 7) << 4)));
#pragma unroll
      for (int nf = 0; nf < 2; ++nf) {
        int rn = w * 32 + nf * 16 + mrow;
        f16x8 bfr = *(const f16x8*)(Bt + rn * 128 + (((kk << 6) + (kg << 4)) ^ ((rn & 7) << 4)));
        acc[nf] = __builtin_amdgcn_mfma_f32_16x16x32_f16(a, bfr, acc[nf], 0, 0, 0);
      }
    }
    __syncthreads();
  }
  // dump pre-LN rows into hs overlay (At/Bt dead now)
  float (*hs)[132] = (float(*)[132])pool;
#pragma unroll
  for (int nf = 0; nf < 2; ++nf)
#pragma unroll
    for (int i = 0; i < 4; ++i)
      hs[kg * 4 + i][w * 32 + nf * 16 + mrow] = acc[nf][i];
  __syncthreads();
  // LN over 128, 16 rows: 16 threads/row, 8 elems each; write t1s (LDS)
  {
    const int r = tid >> 4, g = tid & 15;
    float s1 = 0.f, s2 = 0.f, vals[8];
#pragma unroll
    for (int jj = 0; jj < 8; ++jj) {
      int j = g * 8 + jj;
      float v = hs[r][j] + b1[j];
      vals[jj] = v; s1 += v; s2 += v * v;
    }
#pragma unroll
    for (int m = 1; m < 16; m <<= 1) { s1 += __shfl_xor(s1, m, 64); s2 += __shfl_xor(s2, m, 64); }
    const float mean = s1 * (1.f / 128.f);
    float var = fmaxf(s2 * (1.f / 128.f) - mean * mean, 0.f);
    const float rstd = rsqrtf(var + 1e-12f);
    f16 ov[8];
#pragma unroll
    for (int jj = 0; jj < 8; ++jj) {
      int j = g * 8 + jj;
      float v = (vals[jj] - mean) * rstd * g1[j] + bt1[j];
      ov[jj] = (f16)gelu_exact(v);
    }
    __syncthreads();   // hs reads done; pool front becomes At2
    *(f16x8*)(t1s + r * 256 + ((g * 16) ^ ((r & 7) << 4))) = *(f16x8*)ov;
  }
  __syncthreads();

  // phase2: A = w2T rows l (k=j), B = t1s rows c (k=j). D[l][c].
  char* At2 = pool;   // 128 rows x 256B (16 chunks of 16B per row)
  for (int lc = 0; lc < 4; ++lc) {
    for (int id = tid; id < 2048; id += 256) {
      int r = id >> 4, c = id & 15;
      f16x8 v = *(const f16x8*)(w2T + (lc * 128 + r) * 128 + c * 8);
      *(f16x8*)(At2 + r * 256 + ((c * 16) ^ ((r & 7) << 4))) = v;
    }
    __syncthreads();
    f32x4 acc2[2] = {ZERO4, ZERO4};
#pragma unroll
    for (int ks = 0; ks < 4; ++ks) {
      f16x8 bfr = *(const f16x8*)(t1s + mrow * 256 + (((ks << 6) + (kg << 4)) ^ ((mrow & 7) << 4)));
#pragma unroll
      for (int mf = 0; mf < 2; ++mf) {
        int rm = w * 32 + mf * 16 + mrow;
        f16x8 a = *(const f16x8*)(At2 + rm * 256 + (((ks << 6) + (kg << 4)) ^ ((rm & 7) << 4)));
        acc2[mf] = __builtin_amdgcn_mfma_f32_16x16x32_f16(a, bfr, acc2[mf], 0, 0, 0);
      }
    }
#pragma unroll
    for (int mf = 0; mf < 2; ++mf)
#pragma unroll
      for (int i = 0; i < 4; ++i) {
        int l = lc * 128 + w * 32 + mf * 16 + kg * 4 + i;
        qout[((b << 9) + l) * 256 + c0 + mrow] = (f16)(acc2[mf][i] + sb2[l]);
      }
    __syncthreads();
  }
}

// ---------------------------------------------------------------- K3
// grid 512: b=blk>>4, l0=(blk&15)*32. GEMM3 M=32 l, N=256 k, K=256 c; LN; GEMM4 MFMA; epilogue
__global__ __launch_bounds__(256) void k3_adjust(
    const f16* __restrict__ qbuf, const f16* __restrict__ w3T,
    const float* __restrict__ b3, const float* __restrict__ g3,
    const float* __restrict__ bt3, const f16* __restrict__ w4T,
    const float* __restrict__ b4, const float* __restrict__ offset,
    float* __restrict__ off_out, float* __restrict__ pos_out) {
  __shared__ char pool[50176];     // ph1: At 4KB + Bt 32KB ; ph2: hs 33792B + ts 16384B
  __shared__ char w4t[32 * 512];   // [32 n][256 k f16] swizzled
  __shared__ float sb3[256];
  const int tid = threadIdx.x;
  const int b = blockIdx.x >> 4;
  const int l0 = (blockIdx.x & 15) << 5;
  const int lane = tid & 63, w = tid >> 6;
  const int mh = w & 1, nh = w >> 1;
  const int mrow = lane & 15, kg = lane >> 4;
  char* At = pool;
  char* Bt = pool + 4096;

  for (int id = tid; id < 1024; id += 256) {
    int r = id >> 5, c = id & 31;
    f16x8 v = *(const f16x8*)(w4T + r * 256 + c * 8);
    *(f16x8*)(w4t + r * 512 + ((c * 16) ^ ((r & 7) << 4))) = v;
  }
  sb3[tid] = b3[tid];

  f32x4 acc[8] = {ZERO4, ZERO4, ZERO4, ZERO4, ZERO4, ZERO4, ZERO4, ZERO4};
  for (int s = 0; s < 4; ++s) {
    const int k0 = s << 6;
    {  // At: 32 rows x 8 chunks = 256
      int r = tid >> 3, c = tid & 7;
      f16x8 v = *(const f16x8*)(qbuf + ((b << 9) + l0 + r) * 256 + k0 + c * 8);
      *(f16x8*)(At + r * 128 + ((c * 16) ^ ((r & 7) << 4))) = v;
    }
    for (int id = tid; id < 2048; id += 256) {  // Bt: 256 rows x 8 chunks
      int r = id >> 3, c = id & 7;
      f16x8 v = *(const f16x8*)(w3T + r * 256 + k0 + c * 8);
      *(f16x8*)(Bt + r * 128 + ((c * 16) ^ ((r & 7) << 4))) = v;
    }
    __syncthreads();
#pragma unroll
    for (int kk = 0; kk < 2; ++kk) {
      int arow = mh * 16 + mrow;
      f16x8 a = *(const f16x8*)(At + arow * 128 + (((kk << 6) + (kg << 4)) ^ ((arow & 7) << 4)));
#pragma unroll
      for (int nf = 0; nf < 8; ++nf) {
        int rn = nh * 128 + nf * 16 + mrow;
        f16x8 bfr = *(const f16x8*)(Bt + rn * 128 + (((kk << 6) + (kg << 4)) ^ ((rn & 7) << 4)));
        acc[nf] = __builtin_amdgcn_mfma_f32_16x16x32_f16(a, bfr, acc[nf], 0, 0, 0);
      }
    }
    __syncthreads();
  }
  // phase 2 overlay
  float (*hs)[264] = (float(*)[264])pool;   // [32][264] f32
  char* ts = pool + 33792;                  // [32][256 f16] swizzled, 512B rows
#pragma unroll
  for (int nf = 0; nf < 8; ++nf) {
    int col = nh * 128 + nf * 16 + mrow;
    float bias = sb3[col];
#pragma unroll
    for (int i = 0; i < 4; ++i)
      hs[mh * 16 + kg * 4 + i][col] = acc[nf][i] + bias;
  }
  __syncthreads();
  // LN over 256, 32 rows: 2 passes, 16 threads/row, 16 elems each
  for (int p = 0; p < 2; ++p) {
    const int r = p * 16 + (tid >> 4), g = tid & 15;
    float s1 = 0.f, s2 = 0.f, vals[16];
#pragma unroll
    for (int jj = 0; jj < 16; ++jj) {
      float v = hs[r][g * 16 + jj];
      vals[jj] = v; s1 += v; s2 += v * v;
    }
#pragma unroll
    for (int m = 1; m < 16; m <<= 1) { s1 += __shfl_xor(s1, m, 64); s2 += __shfl_xor(s2, m, 64); }
    const float mean = s1 * (1.f / 256.f);
    float var = fmaxf(s2 * (1.f / 256.f) - mean * mean, 0.f);
    const float rstd = rsqrtf(var + 1e-12f);
    f16 ov[16];
#pragma unroll
    for (int jj = 0; jj < 16; ++jj) {
      int kch = g * 16 + jj;
      float v = (vals[jj] - mean) * rstd * g3[kch] + bt3[kch];
      ov[jj] = (f16)gelu_exact(v);
    }
    *(f16x8*)(ts + r * 512 + ((g * 32) ^ ((r & 7) << 4))) = *(f16x8*)&ov[0];
    *(f16x8*)(ts + r * 512 + ((g * 32 + 16) ^ ((r & 7) << 4))) = *(f16x8*)&ov[8];
  }
  __syncthreads();
  // GEMM4: M=32 l, N=32, K=256. wave: mf=w&1 row-half, n4=w>>1 col-half
  const int mf = w & 1, n4 = w >> 1;
  f32x4 a4 = ZERO4;
#pragma unroll
  for (int ks = 0; ks < 8; ++ks) {
    int ar = mf * 16 + mrow;
    f16x8 a = *(const f16x8*)(ts + ar * 512 + (((ks << 6) + (kg << 4)) ^ ((ar & 7) << 4)));
    int br = n4 * 16 + mrow;
    f16x8 bb = *(const f16x8*)(w4t + br * 512 + (((ks << 6) + (kg << 4)) ^ ((br & 7) << 4)));
    a4 = __builtin_amdgcn_mfma_f32_16x16x32_f16(a, bb, a4, 0, 0, 0);
  }
  const int col = n4 * 16 + mrow;  // 0..31
#pragma unroll
  for (int i = 0; i < 4; ++i) {
    const int row = mf * 16 + kg * 4 + i;
    const int l = l0 + row;
    float adj = tanhf(a4[i] + b4[col]) * 0.02f;
    float padj = __shfl_xor(adj, 1, 64);
    if ((lane & 1) == 0) {
      const int n = col >> 1;
      const float2 offv = *(const float2*)(offset + (((b << 9) + l) << 5) + col);
      const float pos0v = tanhf(offv.x + adj);
      const float ref_y = ((float)n + 0.5f) * ((float)l + 1e-9f) * (1.0f / 4096.0f) - 1.0f;
      const float pos1v = tanhf(offv.y + padj + ref_y);
      *(float2*)(off_out + (((b << 9) + l) << 5) + col) = offv;
      *(float2*)(pos_out + (((b << 9) + l) << 5) + col) = make_float2(pos0v, pos1v);
    }
  }
}

// ---------------------------------------------------------------- K4
__global__ __launch_bounds__(256) void k4_gather(
    const float* __restrict__ x, const float* __restrict__ pos,
    float* __restrict__ outbuf) {
  const unsigned u = blockIdx.x * 256u + threadIdx.x;
  const unsigned t_idx = u >> 6;
  const unsigned cj = u & 63;
  const int b = t_idx >> 13;
  const int l = (t_idx >> 4) & 511;
  const float pos1 = pos[t_idx * 2 + 1];
  const float pix = (pos1 + 1.0f) * 0.5f * 511.0f;
  const float i0f = floorf(pix);
  const int i0 = (int)i0f;
  const float frac = pix - i0f;
  const int i1 = i0 + 1;
  const bool v0 = (i0 >= 0) && (i0 < 512) && (i0 <= l);
  const bool v1 = (i1 >= 0) && (i1 < 512) && (i1 <= l);
  const int c0 = i0 < 0 ? 0 : (i0 > 511 ? 511 : i0);
  const int c1 = i1 < 0 ? 0 : (i1 > 511 ? 511 : i1);
  const float w0  = v0 ? (1.0f - frac) : 0.0f;
  const float w1v = v1 ? frac : 0.0f;
  const float4* x4 = (const float4*)x;
  const float4 va = x4[(unsigned)((b << 9) + c0) * 64u + cj];
  const float4 vb = x4[(unsigned)((b << 9) + c1) * 64u + cj];
  float4 o;
  o.x = w0 * va.x + w1v * vb.x;
  o.y = w0 * va.y + w1v * vb.y;
  o.z = w0 * va.z + w1v * vb.z;
  o.w = w0 * va.w + w1v * vb.w;
  ((float4*)outbuf)[u] = o;
}

extern "C" void kernel_launch(void* const* d_in, const int* in_sizes, int n_in,
                              void* d_out, int out_size, void* d_ws, size_t ws_size,
                              hipStream_t stream) {
  const float* query  = (const float*)d_in[0];
  const float* x      = (const float*)d_in[1];
  const float* offset = (const float*)d_in[2];
  const float* w1  = (const float*)d_in[3];
  const float* b1  = (const float*)d_in[4];
  const float* g1  = (const float*)d_in[5];
  const float* bt1 = (const float*)d_in[6];
  const float* w2  = (const float*)d_in[7];
  const float* b2  = (const float*)d_in[8];
  const float* w3  = (const float*)d_in[9];
  const float* b3  = (const float*)d_in[10];
  const float* g3  = (const float*)d_in[11];
  const float* bt3 = (const float*)d_in[12];
  const float* w4  = (const float*)d_in[13];
  const float* b4  = (const float*)d_in[14];

  float* out     = (float*)d_out;                    // [B,L,N,C] = 67,108,864 f32
  float* off_out = out + 67108864;                   // [B,L,2N]
  float* pos_out = off_out + 524288;                 // [B,L,N,2]

  f16* w1T = (f16*)d_ws;                             // [128][512]
  f16* w2T = w1T + 65536;                            // [512][128]
  f16* w3T = w2T + 65536;                            // [256][256]
  f16* w4T = w3T + 65536;                            // [32][256]
  f16* qT  = w4T + 8192;                             // [32][256][512]
  f16* q   = qT + 4194304;                           // [32][512][256]

  k0_prep<<<1076, 256, 0, stream>>>(w1, w2, w3, w4, query, w1T, w2T, w3T, w4T, qT);
  k12_sample<<<512, 256, 0, stream>>>(qT, w1T, w2T, b1, g1, bt1, b2, q);
  k3_adjust<<<512, 256, 0, stream>>>(q, w3T, b3, g3, bt3, w4T, b4, offset,
                                     off_out, pos_out);
  k4_gather<<<65536, 256, 0, stream>>>(x, pos_out, out);
}

// Round 6
// 114.404 us; speedup vs baseline: 1.0695x; 1.0695x over previous
//
#include <hip/hip_runtime.h>
#include <hip/hip_fp16.h>
#include <math.h>

// AdjustNet: B=32, L=512, C=256, N=16 — f16 MFMA, latency-pipelined
//  K0: transpose+cast weights -> w1T[128][512], w2T[512][128], w3T[256][256], w4T[32][256]
//  K12: per (b, 16-c tile): t1 = gelu(LN_128(query^T@w1+b1)) in LDS; q = t1@w2+b2
//       (query transposed on the fly in LDS; k-step global loads reg-prefetched)
//  K3: h=q@w3+b3, LN_256, gelu -> ts; a=ts@w4+b4 (MFMA); tanh*0.02; pos epilogue
//       (1024 blocks, reg-prefetched staging)
//  K4: out[b,l,n,:] = w0*x[b,c0,:] + w1*x[b,c1,:]  (grid-stride 2048 blocks, NT stores)

typedef _Float16 f16;
typedef _Float16 f16x8 __attribute__((ext_vector_type(8)));
typedef float f32x4 __attribute__((ext_vector_type(4)));

#define ZERO4 f32x4{0.f, 0.f, 0.f, 0.f}

__device__ __forceinline__ float gelu_exact(float v) {
  return 0.5f * v * (1.0f + erff(v * 0.70710678118654752f));
}

// ---------------------------------------------------------------- K0 (weights only)
__global__ __launch_bounds__(256) void k0_prep(
    const float* __restrict__ w1, const float* __restrict__ w2,
    const float* __restrict__ w3, const float* __restrict__ w4,
    f16* __restrict__ w1T, f16* __restrict__ w2T,
    f16* __restrict__ w3T, f16* __restrict__ w4T) {
  __shared__ f16 tile[64][80];
  int blk = blockIdx.x;
  const int tid = threadIdx.x;
  const float* in; f16* out; int R, Cc, tr, tc;
  if (blk < 16)      { in = w1; out = w1T; R = 512; Cc = 128; tr = blk >> 1; tc = blk & 1; }
  else if (blk < 32) { blk -= 16; in = w2; out = w2T; R = 128; Cc = 512; tr = blk >> 3; tc = blk & 7; }
  else if (blk < 48) { blk -= 32; in = w3; out = w3T; R = 256; Cc = 256; tr = blk >> 2; tc = blk & 3; }
  else               { blk -= 48; in = w4; out = w4T; R = 256; Cc = 32;  tr = blk;      tc = 0; }
  const int r0 = tr * 64, c0 = tc * 64;
  for (int id = tid; id < 4096; id += 256) {
    int rr = id >> 6, cc = id & 63;
    if (c0 + cc < Cc) tile[cc][rr] = (f16)in[(r0 + rr) * Cc + c0 + cc];
  }
  __syncthreads();
  for (int id = tid; id < 512; id += 256) {
    int cc = id >> 3, ch = id & 7;
    if (c0 + cc < Cc)
      *(f16x8*)(out + (c0 + cc) * R + r0 + ch * 8) = *(f16x8*)&tile[cc][ch * 8];
  }
}

// ---------------------------------------------------------------- K12
// grid 512: b = blk>>4, c0 = (blk&15)*16.
__global__ __launch_bounds__(256) void k12_sample(
    const float* __restrict__ query, const f16* __restrict__ w1T,
    const f16* __restrict__ w2T,
    const float* __restrict__ b1, const float* __restrict__ g1,
    const float* __restrict__ bt1, const float* __restrict__ b2,
    f16* __restrict__ qout) {
  __shared__ char pool[38912];
  // ph1: At[16 rows x 128B] @0, Bt[128 rows x 128B] @2048; hs overlay @0 (8448B)
  // ph2: At2[128 rows x 256B] @0
  // t1s @32768 (16 x 256B); sb2 @36864 (512 f32)
  const int tid = threadIdx.x;
  const int b = blockIdx.x >> 4;
  const int c0 = (blockIdx.x & 15) << 4;
  const int lane = tid & 63, w = tid >> 6;
  const int mrow = lane & 15, kg = lane >> 4;
  char* At = pool;
  char* Bt = pool + 2048;
  char* t1s = pool + 32768;
  float* sb2 = (float*)(pool + 36864);

  sb2[tid] = b2[tid];
  sb2[tid + 256] = b2[tid + 256];

  // staging thread maps
  const int qll = tid >> 4, qcc = tid & 15;    // query: 4 iters, ll = qll + it*16
  const int wrj = tid >> 3, wch = tid & 7;     // w1T:   4 iters, rj = wrj + it*32

  float qv[4]; f16x8 wv[4];
#pragma unroll
  for (int it = 0; it < 4; ++it) {
    qv[it] = query[(((b << 9) + 0 + qll + it * 16) << 8) + c0 + qcc];
    wv[it] = *(const f16x8*)(w1T + (wrj + it * 32) * 512 + 0 + wch * 8);
  }

  f32x4 acc[2] = {ZERO4, ZERO4};
  for (int s = 0; s < 8; ++s) {
    // write staged regs to LDS (transpose query on the fly)
#pragma unroll
    for (int it = 0; it < 4; ++it) {
      int ll = qll + it * 16;
      *(f16*)(At + qcc * 128 + ((2 * ll) ^ ((qcc & 7) << 4))) = (f16)qv[it];
    }
#pragma unroll
    for (int it = 0; it < 4; ++it) {
      int rj = wrj + it * 32;
      *(f16x8*)(Bt + rj * 128 + ((wch * 16) ^ ((rj & 7) << 4))) = wv[it];
    }
    __syncthreads();
    if (s < 7) {  // prefetch next k-step while MFMAs run
      const int k0n = (s + 1) << 6;
#pragma unroll
      for (int it = 0; it < 4; ++it) {
        qv[it] = query[(((b << 9) + k0n + qll + it * 16) << 8) + c0 + qcc];
        wv[it] = *(const f16x8*)(w1T + (wrj + it * 32) * 512 + k0n + wch * 8);
      }
    }
#pragma unroll
    for (int kk = 0; kk < 2; ++kk) {
      f16x8 a = *(const f16x8*)(At + mrow * 128 + (((kk << 6) + (kg << 4)) ^ ((mrow & 7) << 4)));
#pragma unroll
      for (int nf = 0; nf < 2; ++nf) {
        int rn = w * 32 + nf * 16 + mrow;
        f16x8 bfr = *(const f16x8*)(Bt + rn * 128 + (((kk << 6) + (kg << 4)) ^ ((rn & 7) << 4)));
        acc[nf] = __builtin_amdgcn_mfma_f32_16x16x32_f16(a, bfr, acc[nf], 0, 0, 0);
      }
    }
    __syncthreads();
  }

  // prefetch phase-2 chunk 0 (independent of LDS) — hides under LN
  f16x8 av[8];
#pragma unroll
  for (int it = 0; it < 8; ++it)
    av[it] = *(const f16x8*)(w2T + ((tid >> 4) + it * 16) * 128 + (tid & 15) * 8);

  // dump pre-LN rows into hs overlay (At/Bt dead now)
  float (*hs)[132] = (float(*)[132])pool;
#pragma unroll
  for (int nf = 0; nf < 2; ++nf)
#pragma unroll
    for (int i = 0; i < 4; ++i)
      hs[kg * 4 + i][w * 32 + nf * 16 + mrow] = acc[nf][i];
  __syncthreads();
  // LN over 128, 16 rows: 16 threads/row, 8 elems each -> t1s (LDS)
  {
    const int r = tid >> 4, g = tid & 15;
    float s1 = 0.f, s2 = 0.f, vals[8];
#pragma unroll
    for (int jj = 0; jj < 8; ++jj) {
      int j = g * 8 + jj;
      float v = hs[r][j] + b1[j];
      vals[jj] = v; s1 += v; s2 += v * v;
    }
#pragma unroll
    for (int m = 1; m < 16; m <<= 1) { s1 += __shfl_xor(s1, m, 64); s2 += __shfl_xor(s2, m, 64); }
    const float mean = s1 * (1.f / 128.f);
    float var = fmaxf(s2 * (1.f / 128.f) - mean * mean, 0.f);
    const float rstd = rsqrtf(var + 1e-12f);
    f16 ov[8];
#pragma unroll
    for (int jj = 0; jj < 8; ++jj) {
      int j = g * 8 + jj;
      float v = (vals[jj] - mean) * rstd * g1[j] + bt1[j];
      ov[jj] = (f16)gelu_exact(v);
    }
    __syncthreads();   // hs reads done; pool front becomes At2
    *(f16x8*)(t1s + r * 256 + ((g * 16) ^ ((r & 7) << 4))) = *(f16x8*)ov;
  }
  __syncthreads();

  // phase2: A = w2T rows l (k=j), B = t1s rows c. D[l][c]. 4 chunks of 128 l.
  char* At2 = pool;   // 128 rows x 256B
  const int ar2 = tid >> 4, ac2 = tid & 15;
  for (int lc = 0; lc < 4; ++lc) {
#pragma unroll
    for (int it = 0; it < 8; ++it) {
      int r = ar2 + it * 16;
      *(f16x8*)(At2 + r * 256 + ((ac2 * 16) ^ ((r & 7) << 4))) = av[it];
    }
    __syncthreads();
    if (lc < 3) {
#pragma unroll
      for (int it = 0; it < 8; ++it)
        av[it] = *(const f16x8*)(w2T + ((lc + 1) * 128 + ar2 + it * 16) * 128 + ac2 * 8);
    }
    f32x4 acc2[2] = {ZERO4, ZERO4};
#pragma unroll
    for (int ks = 0; ks < 4; ++ks) {
      f16x8 bfr = *(const f16x8*)(t1s + mrow * 256 + (((ks << 6) + (kg << 4)) ^ ((mrow & 7) << 4)));
#pragma unroll
      for (int mf = 0; mf < 2; ++mf) {
        int rm = w * 32 + mf * 16 + mrow;
        f16x8 a = *(const f16x8*)(At2 + rm * 256 + (((ks << 6) + (kg << 4)) ^ ((rm & 7) << 4)));
        acc2[mf] = __builtin_amdgcn_mfma_f32_16x16x32_f16(a, bfr, acc2[mf], 0, 0, 0);
      }
    }
#pragma unroll
    for (int mf = 0; mf < 2; ++mf)
#pragma unroll
      for (int i = 0; i < 4; ++i) {
        int l = lc * 128 + w * 32 + mf * 16 + kg * 4 + i;
        qout[((b << 9) + l) * 256 + c0 + mrow] = (f16)(acc2[mf][i] + sb2[l]);
      }
    __syncthreads();
  }
}

// ---------------------------------------------------------------- K3
// grid 1024: b=blk>>5, l0=(blk&31)*16. GEMM3 M=16 l, N=256 k, K=256 c; LN; GEMM4; epilogue
__global__ __launch_bounds__(256) void k3_adjust(
    const f16* __restrict__ qbuf, const f16* __restrict__ w3T,
    const float* __restrict__ b3, const float* __restrict__ g3,
    const float* __restrict__ bt3, const f16* __restrict__ w4T,
    const float* __restrict__ b4, const float* __restrict__ offset,
    float* __restrict__ off_out, float* __restrict__ pos_out) {
  __shared__ char pool[34816];     // ph1: At 2KB @0 + Bt 32KB @2048 ; ph2: hs 16896B @0 + ts 8KB @17408
  __shared__ char w4t[32 * 512];   // [32 n][256 k f16] swizzled
  __shared__ float sb3[256];
  const int tid = threadIdx.x;
  const int b = blockIdx.x >> 5;
  const int l0 = (blockIdx.x & 31) << 4;
  const int lane = tid & 63, w = tid >> 6;
  const int mrow = lane & 15, kg = lane >> 4;
  char* At = pool;
  char* Bt = pool + 2048;

  // one-time: w4 tile + b3 into LDS (issued first, in flight under ph1 prefetch)
  for (int id = tid; id < 1024; id += 256) {
    int r = id >> 5, c = id & 31;
    f16x8 v = *(const f16x8*)(w4T + r * 256 + c * 8);
    *(f16x8*)(w4t + r * 512 + ((c * 16) ^ ((r & 7) << 4))) = v;
  }
  sb3[tid] = b3[tid];

  const int sr = tid >> 3, sc = tid & 7;   // At: tid<128 one chunk; Bt: 8 iters r = sr + it*32
  f16x8 aq; f16x8 bq[8];
  if (tid < 128) aq = *(const f16x8*)(qbuf + ((b << 9) + l0 + sr) * 256 + 0 + sc * 8);
#pragma unroll
  for (int it = 0; it < 8; ++it)
    bq[it] = *(const f16x8*)(w3T + (sr + it * 32) * 256 + 0 + sc * 8);

  f32x4 acc[4] = {ZERO4, ZERO4, ZERO4, ZERO4};
  for (int s = 0; s < 4; ++s) {
    if (tid < 128)
      *(f16x8*)(At + sr * 128 + ((sc * 16) ^ ((sr & 7) << 4))) = aq;
#pragma unroll
    for (int it = 0; it < 8; ++it) {
      int r = sr + it * 32;
      *(f16x8*)(Bt + r * 128 + ((sc * 16) ^ ((r & 7) << 4))) = bq[it];
    }
    __syncthreads();
    if (s < 3) {
      const int k0n = (s + 1) << 6;
      if (tid < 128) aq = *(const f16x8*)(qbuf + ((b << 9) + l0 + sr) * 256 + k0n + sc * 8);
#pragma unroll
      for (int it = 0; it < 8; ++it)
        bq[it] = *(const f16x8*)(w3T + (sr + it * 32) * 256 + k0n + sc * 8);
    }
#pragma unroll
    for (int kk = 0; kk < 2; ++kk) {
      f16x8 a = *(const f16x8*)(At + mrow * 128 + (((kk << 6) + (kg << 4)) ^ ((mrow & 7) << 4)));
#pragma unroll
      for (int nf = 0; nf < 4; ++nf) {
        int rn = w * 64 + nf * 16 + mrow;
        f16x8 bfr = *(const f16x8*)(Bt + rn * 128 + (((kk << 6) + (kg << 4)) ^ ((rn & 7) << 4)));
        acc[nf] = __builtin_amdgcn_mfma_f32_16x16x32_f16(a, bfr, acc[nf], 0, 0, 0);
      }
    }
    __syncthreads();
  }
  // phase 2 overlay
  float (*hs)[264] = (float(*)[264])pool;   // [16][264] f32
  char* ts = pool + 17408;                  // [16][512B] swizzled
#pragma unroll
  for (int nf = 0; nf < 4; ++nf) {
    int col = w * 64 + nf * 16 + mrow;
    float bias = sb3[col];
#pragma unroll
    for (int i = 0; i < 4; ++i)
      hs[kg * 4 + i][col] = acc[nf][i] + bias;
  }
  __syncthreads();
  // LN over 256, 16 rows: 16 threads/row, 16 elems each
  {
    const int r = tid >> 4, g = tid & 15;
    float s1 = 0.f, s2 = 0.f, vals[16];
#pragma unroll
    for (int jj = 0; jj < 16; ++jj) {
      float v = hs[r][g * 16 + jj];
      vals[jj] = v; s1 += v; s2 += v * v;
    }
#pragma unroll
    for (int m = 1; m < 16; m <<= 1) { s1 += __shfl_xor(s1, m, 64); s2 += __shfl_xor(s2, m, 64); }
    const float mean = s1 * (1.f / 256.f);
    float var = fmaxf(s2 * (1.f / 256.f) - mean * mean, 0.f);
    const float rstd = rsqrtf(var + 1e-12f);
    f16 ov[16];
#pragma unroll
    for (int jj = 0; jj < 16; ++jj) {
      int kch = g * 16 + jj;
      float v = (vals[jj] - mean) * rstd * g3[kch] + bt3[kch];
      ov[jj] = (f16)gelu_exact(v);
    }
    *(f16x8*)(ts + r * 512 + ((g * 32) ^ ((r & 7) << 4))) = *(f16x8*)&ov[0];
    *(f16x8*)(ts + r * 512 + ((g * 32 + 16) ^ ((r & 7) << 4))) = *(f16x8*)&ov[8];
  }
  __syncthreads();
  // GEMM4: M=16 l, N=32, K=256 — waves 0,1 only (tiny)
  if (w < 2) {
    const int n4 = w;
    f32x4 a4 = ZERO4;
#pragma unroll
    for (int ks = 0; ks < 8; ++ks) {
      f16x8 a = *(const f16x8*)(ts + mrow * 512 + (((ks << 6) + (kg << 4)) ^ ((mrow & 7) << 4)));
      int br = n4 * 16 + mrow;
      f16x8 bb = *(const f16x8*)(w4t + br * 512 + (((ks << 6) + (kg << 4)) ^ ((br & 7) << 4)));
      a4 = __builtin_amdgcn_mfma_f32_16x16x32_f16(a, bb, a4, 0, 0, 0);
    }
    const int col = n4 * 16 + mrow;  // 0..31
#pragma unroll
    for (int i = 0; i < 4; ++i) {
      const int row = kg * 4 + i;
      const int l = l0 + row;
      float adj = tanhf(a4[i] + b4[col]) * 0.02f;
      float padj = __shfl_xor(adj, 1, 64);
      if ((lane & 1) == 0) {
        const int n = col >> 1;
        const float2 offv = *(const float2*)(offset + (((b << 9) + l) << 5) + col);
        const float pos0v = tanhf(offv.x + adj);
        const float ref_y = ((float)n + 0.5f) * ((float)l + 1e-9f) * (1.0f / 4096.0f) - 1.0f;
        const float pos1v = tanhf(offv.y + padj + ref_y);
        *(float2*)(off_out + (((b << 9) + l) << 5) + col) = offv;
        *(float2*)(pos_out + (((b << 9) + l) << 5) + col) = make_float2(pos0v, pos1v);
      }
    }
  }
}

// ---------------------------------------------------------------- K4 (grid-stride)
__global__ __launch_bounds__(256) void k4_gather(
    const float* __restrict__ x, const float* __restrict__ pos,
    float* __restrict__ outbuf) {
  const unsigned tbase = blockIdx.x * 256u + threadIdx.x;
  for (unsigned u = tbase; u < 16777216u; u += 524288u) {
    const unsigned t_idx = u >> 6;
    const unsigned cj = u & 63;
    const int b = t_idx >> 13;
    const int l = (t_idx >> 4) & 511;
    const float pos1 = pos[t_idx * 2 + 1];
    const float pix = (pos1 + 1.0f) * 0.5f * 511.0f;
    const float i0f = floorf(pix);
    const int i0 = (int)i0f;
    const float frac = pix - i0f;
    const int i1 = i0 + 1;
    const bool v0 = (i0 >= 0) && (i0 < 512) && (i0 <= l);
    const bool v1 = (i1 >= 0) && (i1 < 512) && (i1 <= l);
    const int c0 = i0 < 0 ? 0 : (i0 > 511 ? 511 : i0);
    const int c1 = i1 < 0 ? 0 : (i1 > 511 ? 511 : i1);
    const float w0  = v0 ? (1.0f - frac) : 0.0f;
    const float w1v = v1 ? frac : 0.0f;
    const f32x4* x4 = (const f32x4*)x;
    const f32x4 va = x4[(unsigned)((b << 9) + c0) * 64u + cj];
    const f32x4 vb = x4[(unsigned)((b << 9) + c1) * 64u + cj];
    f32x4 o = w0 * va + w1v * vb;
    __builtin_nontemporal_store(o, (f32x4*)outbuf + u);
  }
}

extern "C" void kernel_launch(void* const* d_in, const int* in_sizes, int n_in,
                              void* d_out, int out_size, void* d_ws, size_t ws_size,
                              hipStream_t stream) {
  const float* query  = (const float*)d_in[0];
  const float* x      = (const float*)d_in[1];
  const float* offset = (const float*)d_in[2];
  const float* w1  = (const float*)d_in[3];
  const float* b1  = (const float*)d_in[4];
  const float* g1  = (const float*)d_in[5];
  const float* bt1 = (const float*)d_in[6];
  const float* w2  = (const float*)d_in[7];
  const float* b2  = (const float*)d_in[8];
  const float* w3  = (const float*)d_in[9];
  const float* b3  = (const float*)d_in[10];
  const float* g3  = (const float*)d_in[11];
  const float* bt3 = (const float*)d_in[12];
  const float* w4  = (const float*)d_in[13];
  const float* b4  = (const float*)d_in[14];

  float* out     = (float*)d_out;                    // [B,L,N,C] = 67,108,864 f32
  float* off_out = out + 67108864;                   // [B,L,2N]
  float* pos_out = off_out + 524288;                 // [B,L,N,2]

  f16* w1T = (f16*)d_ws;                             // [128][512]
  f16* w2T = w1T + 65536;                            // [512][128]
  f16* w3T = w2T + 65536;                            // [256][256]
  f16* w4T = w3T + 65536;                            // [32][256]
  f16* q   = w4T + 8192;                             // [32][512][256]

  k0_prep<<<52, 256, 0, stream>>>(w1, w2, w3, w4, w1T, w2T, w3T, w4T);
  k12_sample<<<512, 256, 0, stream>>>(query, w1T, w2T, b1, g1, bt1, b2, q);
  k3_adjust<<<1024, 256, 0, stream>>>(q, w3T, b3, g3, bt3, w4T, b4, offset,
                                      off_out, pos_out);
  k4_gather<<<2048, 256, 0, stream>>>(x, pos_out, out);
}